// Round 8
// baseline (496.799 us; speedup 1.0000x reference)
//
#include <hip/hip_runtime.h>
#include <hip/hip_bf16.h>

using bf16x8 = __attribute__((ext_vector_type(8))) __bf16;
using f32x4  = __attribute__((ext_vector_type(4))) float;
typedef unsigned short ushort_t;

#define M_DIM 16384
#define K_DIM 4096
#define N_DIM 1024

#define BARR() __builtin_amdgcn_s_barrier()

__device__ __forceinline__ unsigned short f2bf(float f) {
  __hip_bfloat16 h = __float2bfloat16(f);  // RNE
  return *reinterpret_cast<unsigned short*>(&h);
}

__device__ __forceinline__ float snap(float a) {
  float q = 0.0f;
  q += (a > 0.25f) ? 0.5f : 0.0f;
  q += (a > 0.75f) ? 0.5f : 0.0f;
  q += (a > 1.25f) ? 0.5f : 0.0f;
  q += (a > 1.75f) ? 0.5f : 0.0f;
  q += (a > 2.5f)  ? 1.0f : 0.0f;
  q += (a > 3.5f)  ? 1.0f : 0.0f;
  q += (a > 5.0f)  ? 2.0f : 0.0f;
  return q;
}

__device__ __forceinline__ unsigned short qdq(float xv, float rs, float scale) {
  float xs = xv * rs;
  float q  = copysignf(snap(fabsf(xs)), xs);
  return f2bf(q * scale);
}

__global__ __launch_bounds__(256) void quant_kernel(const float* __restrict__ x,
                                                    unsigned short* __restrict__ dq) {
  const int wid = (blockIdx.x << 2) + (threadIdx.x >> 6);
  const int l   = threadIdx.x & 63;
  const int sub = l >> 4, t = l & 15;
  const size_t base = ((size_t)wid * 4 + sub) * 128;
  const float4* px = reinterpret_cast<const float4*>(x + base);
  float4 v0 = px[t];
  float4 v1 = px[16 + t];
  float amax = fmaxf(fmaxf(fmaxf(fabsf(v0.x), fabsf(v0.y)), fmaxf(fabsf(v0.z), fabsf(v0.w))),
                     fmaxf(fmaxf(fabsf(v1.x), fabsf(v1.y)), fmaxf(fabsf(v1.z), fabsf(v1.w))));
  #pragma unroll
  for (int m = 1; m < 16; m <<= 1) amax = fmaxf(amax, __shfl_xor(amax, m, 64));
  float scale = amax / 6.0f;
  if (scale == 0.0f) scale = 1.0f;
  const float rs = 1.0f / scale;
  ushort4 o0, o1;
  o0.x = qdq(v0.x, rs, scale); o0.y = qdq(v0.y, rs, scale);
  o0.z = qdq(v0.z, rs, scale); o0.w = qdq(v0.w, rs, scale);
  o1.x = qdq(v1.x, rs, scale); o1.y = qdq(v1.y, rs, scale);
  o1.z = qdq(v1.z, rs, scale); o1.w = qdq(v1.w, rs, scale);
  reinterpret_cast<ushort4*>(dq + base)[t]      = o0;
  reinterpret_cast<ushort4*>(dq + base)[16 + t] = o1;
}

__global__ __launch_bounds__(256) void wconv_kernel(const float* __restrict__ w,
                                                    unsigned short* __restrict__ o) {
  const int n4 = (N_DIM * K_DIM) / 4;
  for (int i = blockIdx.x * 256 + threadIdx.x; i < n4; i += gridDim.x * 256) {
    float4 v = reinterpret_cast<const float4*>(w)[i];
    ushort4 u;
    u.x = f2bf(v.x); u.y = f2bf(v.y); u.z = f2bf(v.z); u.w = f2bf(v.w);
    reinterpret_cast<ushort4*>(o)[i] = u;
  }
}

__device__ __forceinline__ bf16x8 lds_ld(const ushort_t* p) {
  return *reinterpret_cast<const bf16x8*>(p);
}

__device__ __forceinline__ void stg(const ushort_t* g0, const ushort_t* g1,
                                    ushort_t (&slot)[8192], int wid) {
  __builtin_amdgcn_global_load_lds((const __attribute__((address_space(1))) void*)g0,
      (__attribute__((address_space(3))) void*)(&slot[wid * 512]), 16, 0, 0);
  __builtin_amdgcn_global_load_lds((const __attribute__((address_space(1))) void*)g1,
      (__attribute__((address_space(3))) void*)(&slot[4096 + wid * 512]), 16, 0, 0);
}

// ===================== REAL GEMM (R6, best known: 167 us) =====================
template<bool S12, bool S34, int VM>
__device__ __forceinline__ void tile_iter(
    int t,
    ushort_t (&rA)[8192],  ushort_t (&rB)[8192],
    ushort_t (&dB1)[8192], ushort_t (&dA1)[8192],
    ushort_t (&dB0)[8192], ushort_t (&dA0)[8192],
    int wid, const int (&roA)[8], const int (&roB)[4], int swz0, int swz1,
    const ushort_t* pa0, const ushort_t* pa1,
    const ushort_t* pb0, const ushort_t* pb1,
    f32x4 (&acc)[8][4]) {
  bf16x8 aL0[4], aL1[4], aH0[4], aH1[4], b0[4], b1[4];

  #pragma unroll
  for (int i = 0; i < 4; ++i) {
    aL0[i] = lds_ld(&rA[roA[i] + swz0]);
    aL1[i] = lds_ld(&rA[roA[i] + swz1]);
  }
  #pragma unroll
  for (int n = 0; n < 2; ++n) {
    b0[n] = lds_ld(&rB[roB[n] + swz0]);
    b1[n] = lds_ld(&rB[roB[n] + swz1]);
  }

  // ph1
  #pragma unroll
  for (int n = 2; n < 4; ++n) {
    b0[n] = lds_ld(&rB[roB[n] + swz0]);
    b1[n] = lds_ld(&rB[roB[n] + swz1]);
  }
  if constexpr (S12)
    stg(pb0 + (size_t)128 * K_DIM + (size_t)(t + 1) * 64,
        pb1 + (size_t)128 * K_DIM + (size_t)(t + 1) * 64, dB1, wid);
  __builtin_amdgcn_s_setprio(1);
  #pragma unroll
  for (int i = 0; i < 4; ++i)
    #pragma unroll
    for (int n = 0; n < 2; ++n) {
      acc[i][n] = __builtin_amdgcn_mfma_f32_16x16x32_bf16(aL0[i], b0[n], acc[i][n], 0, 0, 0);
      acc[i][n] = __builtin_amdgcn_mfma_f32_16x16x32_bf16(aL1[i], b1[n], acc[i][n], 0, 0, 0);
    }
  __builtin_amdgcn_s_setprio(0);
  BARR();

  // ph2
  #pragma unroll
  for (int i = 0; i < 4; ++i) {
    aH0[i] = lds_ld(&rA[roA[4 + i] + swz0]);
    aH1[i] = lds_ld(&rA[roA[4 + i] + swz1]);
  }
  if constexpr (S12)
    stg(pa0 + (size_t)128 * K_DIM + (size_t)(t + 1) * 64,
        pa1 + (size_t)128 * K_DIM + (size_t)(t + 1) * 64, dA1, wid);
  __builtin_amdgcn_s_setprio(1);
  #pragma unroll
  for (int i = 0; i < 4; ++i)
    #pragma unroll
    for (int n = 2; n < 4; ++n) {
      acc[i][n] = __builtin_amdgcn_mfma_f32_16x16x32_bf16(aL0[i], b0[n], acc[i][n], 0, 0, 0);
      acc[i][n] = __builtin_amdgcn_mfma_f32_16x16x32_bf16(aL1[i], b1[n], acc[i][n], 0, 0, 0);
    }
  __builtin_amdgcn_s_setprio(0);
  BARR();

  // ph3
  if constexpr (S34)
    stg(pb0 + (size_t)(t + 2) * 64, pb1 + (size_t)(t + 2) * 64, dB0, wid);
  __builtin_amdgcn_s_setprio(1);
  #pragma unroll
  for (int i = 0; i < 4; ++i)
    #pragma unroll
    for (int n = 2; n < 4; ++n) {
      acc[4 + i][n] = __builtin_amdgcn_mfma_f32_16x16x32_bf16(aH0[i], b0[n], acc[4 + i][n], 0, 0, 0);
      acc[4 + i][n] = __builtin_amdgcn_mfma_f32_16x16x32_bf16(aH1[i], b1[n], acc[4 + i][n], 0, 0, 0);
    }
  __builtin_amdgcn_s_setprio(0);
  BARR();

  // ph4
  if constexpr (S34)
    stg(pa0 + (size_t)(t + 2) * 64, pa1 + (size_t)(t + 2) * 64, dA0, wid);
  __builtin_amdgcn_s_setprio(1);
  #pragma unroll
  for (int i = 0; i < 4; ++i)
    #pragma unroll
    for (int n = 0; n < 2; ++n) {
      acc[4 + i][n] = __builtin_amdgcn_mfma_f32_16x16x32_bf16(aH0[i], b0[n], acc[4 + i][n], 0, 0, 0);
      acc[4 + i][n] = __builtin_amdgcn_mfma_f32_16x16x32_bf16(aH1[i], b1[n], acc[4 + i][n], 0, 0, 0);
    }
  __builtin_amdgcn_s_setprio(0);
  if constexpr (VM == 4) {
    asm volatile("s_waitcnt vmcnt(4)");
    __builtin_amdgcn_sched_barrier(0);
  } else if constexpr (VM == 0) {
    asm volatile("s_waitcnt vmcnt(0)");
    __builtin_amdgcn_sched_barrier(0);
  }
  BARR();
}

template<int WM, int WH>
__device__ __forceinline__ void krun(
    ushort_t (&sA0p0)[8192], ushort_t (&sA0p1)[8192],
    ushort_t (&sA1p0)[8192], ushort_t (&sA1p1)[8192],
    ushort_t (&sB0p0)[8192], ushort_t (&sB0p1)[8192],
    ushort_t (&sB1p0)[8192], ushort_t (&sB1p1)[8192],
    int wid, const int (&roA)[8], const int (&roB)[4], int swz0, int swz1,
    const ushort_t* pa0, const ushort_t* pa1,
    const ushort_t* pb0, const ushort_t* pb1,
    f32x4 (&acc)[8][4]) {
  ushort_t (&rAp0)[8192] = WM ? sA1p0 : sA0p0;
  ushort_t (&rAp1)[8192] = WM ? sA1p1 : sA0p1;
  ushort_t (&rBp0)[8192] = WH ? sB1p0 : sB0p0;
  ushort_t (&rBp1)[8192] = WH ? sB1p1 : sB0p1;

  stg(pb0, pb1, sB0p0, wid);
  stg(pa0, pa1, sA0p0, wid);
  stg(pb0 + (size_t)128 * K_DIM, pb1 + (size_t)128 * K_DIM, sB1p0, wid);
  stg(pa0 + (size_t)128 * K_DIM, pa1 + (size_t)128 * K_DIM, sA1p0, wid);
  stg(pb0 + 64, pb1 + 64, sB0p1, wid);
  stg(pa0 + 64, pa1 + 64, sA0p1, wid);
  asm volatile("s_waitcnt vmcnt(4)");
  __builtin_amdgcn_sched_barrier(0);
  BARR();

  for (int t = 0; t < 62; t += 2) {
    tile_iter<true, true, 4>(t,     rAp0, rBp0, sB1p1, sA1p1, sB0p0, sA0p0,
                             wid, roA, roB, swz0, swz1, pa0, pa1, pb0, pb1, acc);
    tile_iter<true, true, 4>(t + 1, rAp1, rBp1, sB1p0, sA1p0, sB0p1, sA0p1,
                             wid, roA, roB, swz0, swz1, pa0, pa1, pb0, pb1, acc);
  }
  tile_iter<true, false, 0>(62, rAp0, rBp0, sB1p1, sA1p1, sB0p0, sA0p0,
                            wid, roA, roB, swz0, swz1, pa0, pa1, pb0, pb1, acc);
  tile_iter<false, false, -1>(63, rAp1, rBp1, sB1p0, sA1p0, sB0p1, sA0p1,
                              wid, roA, roB, swz0, swz1, pa0, pa1, pb0, pb1, acc);
}

__global__ __launch_bounds__(512, 2) void gemm256(const ushort_t* __restrict__ A,
                                                  const ushort_t* __restrict__ B,
                                                  const float* __restrict__ bias,
                                                  float* __restrict__ C) {
  __shared__ ushort_t sA0p0[8192], sA0p1[8192], sA1p0[8192], sA1p1[8192];
  __shared__ ushort_t sB0p0[8192], sB0p1[8192], sB1p0[8192], sB1p1[8192];
  const int tid  = threadIdx.x;
  const int wid  = tid >> 6, lane = tid & 63;
  const int r    = lane & 15, h = lane >> 4;
  const int wm   = wid >> 2, wn = wid & 3;
  const int bn   = blockIdx.x, bm = blockIdx.y;

  const int x7   = lane & 7;
  const int swz0 = ((h) ^ x7) << 3;
  const int swz1 = ((4 | h) ^ x7) << 3;
  int roA[8], roB[4];
  #pragma unroll
  for (int m = 0; m < 8; ++m) roA[m] = (m * 16 + r) * 64;
  #pragma unroll
  for (int n = 0; n < 4; ++n) roB[n] = ((wn & 1) * 64 + n * 16 + r) * 64;

  const int srow0 = tid >> 3;
  const int cst   = ((tid & 7) ^ (srow0 & 7)) << 3;
  const ushort_t* pa0 = A + (size_t)(bm * 256 + srow0) * K_DIM + cst;
  const ushort_t* pa1 = A + (size_t)(bm * 256 + 64 + srow0) * K_DIM + cst;
  const ushort_t* pb0 = B + (size_t)(bn * 256 + srow0) * K_DIM + cst;
  const ushort_t* pb1 = B + (size_t)(bn * 256 + 64 + srow0) * K_DIM + cst;

  f32x4 acc[8][4];
  #pragma unroll
  for (int m = 0; m < 8; ++m)
    #pragma unroll
    for (int n = 0; n < 4; ++n) acc[m][n] = (f32x4){0.f, 0.f, 0.f, 0.f};

  const int wh = wn >> 1;
  if (wm == 0) {
    if (wh == 0) krun<0, 0>(sA0p0, sA0p1, sA1p0, sA1p1, sB0p0, sB0p1, sB1p0, sB1p1,
                            wid, roA, roB, swz0, swz1, pa0, pa1, pb0, pb1, acc);
    else         krun<0, 1>(sA0p0, sA0p1, sA1p0, sA1p1, sB0p0, sB0p1, sB1p0, sB1p1,
                            wid, roA, roB, swz0, swz1, pa0, pa1, pb0, pb1, acc);
  } else {
    if (wh == 0) krun<1, 0>(sA0p0, sA0p1, sA1p0, sA1p1, sB0p0, sB0p1, sB1p0, sB1p1,
                            wid, roA, roB, swz0, swz1, pa0, pa1, pb0, pb1, acc);
    else         krun<1, 1>(sA0p0, sA0p1, sA1p0, sA1p1, sB0p0, sB0p1, sB1p0, sB1p1,
                            wid, roA, roB, swz0, swz1, pa0, pa1, pb0, pb1, acc);
  }

  const int orow = bm * 256 + wm * 128;
  const int ocol = bn * 256 + wn * 64;
  #pragma unroll
  for (int n = 0; n < 4; ++n) {
    const int col = ocol + n * 16 + r;
    const float bv = bias[col];
    #pragma unroll
    for (int m = 0; m < 8; ++m) {
      const int rb = orow + m * 16 + h * 4;
      #pragma unroll
      for (int j = 0; j < 4; ++j)
        C[(size_t)(rb + j) * N_DIM + col] = acc[m][n][j] + bv;
    }
  }
}

// ===================== DIAGNOSTIC VARIANTS (write garbage to scratch) =========
// Shared epilogue for variants.
__device__ __forceinline__ void vepi(f32x4 (&acc)[8][4], float* D, int bm, int bn,
                                     int wm, int wn, int r, int h) {
  const int orow = bm * 256 + wm * 128;
  const int ocol = bn * 256 + wn * 64;
  #pragma unroll
  for (int n = 0; n < 4; ++n) {
    const int col = ocol + n * 16 + r;
    #pragma unroll
    for (int m = 0; m < 8; ++m) {
      const int rb = orow + m * 16 + h * 4;
      #pragma unroll
      for (int j = 0; j < 4; ++j)
        D[(size_t)(rb + j) * N_DIM + col] = acc[m][n][j];
    }
  }
}

// 16-MFMA cluster using a fixed small frag set (data values irrelevant).
__device__ __forceinline__ void vmfma(f32x4 (&acc)[8][4], bf16x8 (&f0)[4], bf16x8 (&f1)[4],
                                      bf16x8 (&g0)[2], bf16x8 (&g1)[2], int mb, int nb) {
  __builtin_amdgcn_s_setprio(1);
  #pragma unroll
  for (int i = 0; i < 4; ++i)
    #pragma unroll
    for (int n = 0; n < 2; ++n) {
      acc[mb + i][nb + n] = __builtin_amdgcn_mfma_f32_16x16x32_bf16(f0[i], g0[n], acc[mb + i][nb + n], 0, 0, 0);
      acc[mb + i][nb + n] = __builtin_amdgcn_mfma_f32_16x16x32_bf16(f1[i], g1[n], acc[mb + i][nb + n], 0, 0, 0);
    }
  __builtin_amdgcn_s_setprio(0);
}

// V1: MFMA + 4-barrier cadence only (no per-tile reads, no steady staging).
__global__ __launch_bounds__(512, 2) void gv1_mfma(const ushort_t* __restrict__ A,
                                                   const ushort_t* __restrict__ B,
                                                   float* __restrict__ D) {
  __shared__ ushort_t sA[8192], sB[8192];
  const int tid = threadIdx.x, wid = tid >> 6, lane = tid & 63;
  const int r = lane & 15, h = lane >> 4, wm = wid >> 2, wn = wid & 3;
  const int bn = blockIdx.x, bm = blockIdx.y;
  const int x7 = lane & 7;
  const int swz0 = ((h) ^ x7) << 3, swz1 = ((4 | h) ^ x7) << 3;
  const int srow0 = tid >> 3;
  const int cst = ((tid & 7) ^ (srow0 & 7)) << 3;
  const ushort_t* pa0 = A + (size_t)(bm * 256 + srow0) * K_DIM + cst;
  const ushort_t* pa1 = A + (size_t)(bm * 256 + 64 + srow0) * K_DIM + cst;
  const ushort_t* pb0 = B + (size_t)(bn * 256 + srow0) * K_DIM + cst;
  const ushort_t* pb1 = B + (size_t)(bn * 256 + 64 + srow0) * K_DIM + cst;
  stg(pb0, pb1, sB, wid);
  stg(pa0, pa1, sA, wid);
  asm volatile("s_waitcnt vmcnt(0)");
  BARR();
  bf16x8 f0[4], f1[4];
  bf16x8 g0[2], g1[2];
  #pragma unroll
  for (int i = 0; i < 4; ++i) {
    f0[i] = lds_ld(&sA[(i * 16 + r) * 64 + swz0]);
    f1[i] = lds_ld(&sA[(i * 16 + r) * 64 + swz1]);
  }
  #pragma unroll
  for (int n = 0; n < 2; ++n) {
    g0[n] = lds_ld(&sB[((wn & 1) * 64 + n * 16 + r) * 64 + swz0]);
    g1[n] = lds_ld(&sB[((wn & 1) * 64 + n * 16 + r) * 64 + swz1]);
  }
  f32x4 acc[8][4];
  #pragma unroll
  for (int m = 0; m < 8; ++m)
    #pragma unroll
    for (int n = 0; n < 4; ++n) acc[m][n] = (f32x4){0.f, 0.f, 0.f, 0.f};
  for (int t = 0; t < 64; ++t) {
    vmfma(acc, f0, f1, g0, g1, 0, 0); BARR();
    vmfma(acc, f0, f1, g0, g1, 0, 2); BARR();
    vmfma(acc, f0, f1, g0, g1, 4, 2); BARR();
    vmfma(acc, f0, f1, g0, g1, 4, 0); BARR();
  }
  vepi(acc, D, bm, bn, wm, wn, r, h);
}

// V2: + real per-tile ds_read stream (24 x b128, R6 distribution), no staging.
__global__ __launch_bounds__(512, 2) void gv2_reads(const ushort_t* __restrict__ A,
                                                    const ushort_t* __restrict__ B,
                                                    float* __restrict__ D) {
  __shared__ ushort_t sA[8192], sB[8192];
  const int tid = threadIdx.x, wid = tid >> 6, lane = tid & 63;
  const int r = lane & 15, h = lane >> 4, wm = wid >> 2, wn = wid & 3;
  const int bn = blockIdx.x, bm = blockIdx.y;
  const int x7 = lane & 7;
  const int swz0 = ((h) ^ x7) << 3, swz1 = ((4 | h) ^ x7) << 3;
  int roA[8], roB[4];
  #pragma unroll
  for (int m = 0; m < 8; ++m) roA[m] = (m * 16 + r) * 64;
  #pragma unroll
  for (int n = 0; n < 4; ++n) roB[n] = ((wn & 1) * 64 + n * 16 + r) * 64;
  const int srow0 = tid >> 3;
  const int cst = ((tid & 7) ^ (srow0 & 7)) << 3;
  const ushort_t* pa0 = A + (size_t)(bm * 256 + srow0) * K_DIM + cst;
  const ushort_t* pa1 = A + (size_t)(bm * 256 + 64 + srow0) * K_DIM + cst;
  const ushort_t* pb0 = B + (size_t)(bn * 256 + srow0) * K_DIM + cst;
  const ushort_t* pb1 = B + (size_t)(bn * 256 + 64 + srow0) * K_DIM + cst;
  stg(pb0, pb1, sB, wid);
  stg(pa0, pa1, sA, wid);
  asm volatile("s_waitcnt vmcnt(0)");
  BARR();
  f32x4 acc[8][4];
  #pragma unroll
  for (int m = 0; m < 8; ++m)
    #pragma unroll
    for (int n = 0; n < 4; ++n) acc[m][n] = (f32x4){0.f, 0.f, 0.f, 0.f};
  unsigned off = 0;
  for (int t = 0; t < 64; ++t) {
    asm volatile("" : "+v"(off));   // defeat LICM: reads must re-issue each tile
    bf16x8 aL0[4], aL1[4], aH0[4], aH1[4], b0[4], b1[4];
    #pragma unroll
    for (int i = 0; i < 4; ++i) {
      aL0[i] = lds_ld(&sA[roA[i] + swz0 + off]);
      aL1[i] = lds_ld(&sA[roA[i] + swz1 + off]);
    }
    #pragma unroll
    for (int n = 0; n < 2; ++n) {
      b0[n] = lds_ld(&sB[roB[n] + swz0 + off]);
      b1[n] = lds_ld(&sB[roB[n] + swz1 + off]);
    }
    // ph1
    #pragma unroll
    for (int n = 2; n < 4; ++n) {
      b0[n] = lds_ld(&sB[roB[n] + swz0 + off]);
      b1[n] = lds_ld(&sB[roB[n] + swz1 + off]);
    }
    __builtin_amdgcn_s_setprio(1);
    #pragma unroll
    for (int i = 0; i < 4; ++i)
      #pragma unroll
      for (int n = 0; n < 2; ++n) {
        acc[i][n] = __builtin_amdgcn_mfma_f32_16x16x32_bf16(aL0[i], b0[n], acc[i][n], 0, 0, 0);
        acc[i][n] = __builtin_amdgcn_mfma_f32_16x16x32_bf16(aL1[i], b1[n], acc[i][n], 0, 0, 0);
      }
    __builtin_amdgcn_s_setprio(0);
    BARR();
    // ph2
    #pragma unroll
    for (int i = 0; i < 4; ++i) {
      aH0[i] = lds_ld(&sA[roA[4 + i] + swz0 + off]);
      aH1[i] = lds_ld(&sA[roA[4 + i] + swz1 + off]);
    }
    __builtin_amdgcn_s_setprio(1);
    #pragma unroll
    for (int i = 0; i < 4; ++i)
      #pragma unroll
      for (int n = 2; n < 4; ++n) {
        acc[i][n] = __builtin_amdgcn_mfma_f32_16x16x32_bf16(aL0[i], b0[n], acc[i][n], 0, 0, 0);
        acc[i][n] = __builtin_amdgcn_mfma_f32_16x16x32_bf16(aL1[i], b1[n], acc[i][n], 0, 0, 0);
      }
    __builtin_amdgcn_s_setprio(0);
    BARR();
    // ph3
    __builtin_amdgcn_s_setprio(1);
    #pragma unroll
    for (int i = 0; i < 4; ++i)
      #pragma unroll
      for (int n = 2; n < 4; ++n) {
        acc[4 + i][n] = __builtin_amdgcn_mfma_f32_16x16x32_bf16(aH0[i], b0[n], acc[4 + i][n], 0, 0, 0);
        acc[4 + i][n] = __builtin_amdgcn_mfma_f32_16x16x32_bf16(aH1[i], b1[n], acc[4 + i][n], 0, 0, 0);
      }
    __builtin_amdgcn_s_setprio(0);
    BARR();
    // ph4
    __builtin_amdgcn_s_setprio(1);
    #pragma unroll
    for (int i = 0; i < 4; ++i)
      #pragma unroll
      for (int n = 0; n < 2; ++n) {
        acc[4 + i][n] = __builtin_amdgcn_mfma_f32_16x16x32_bf16(aH0[i], b0[n], acc[4 + i][n], 0, 0, 0);
        acc[4 + i][n] = __builtin_amdgcn_mfma_f32_16x16x32_bf16(aH1[i], b1[n], acc[4 + i][n], 0, 0, 0);
      }
    __builtin_amdgcn_s_setprio(0);
    BARR();
  }
  vepi(acc, D, bm, bn, wm, wn, r, h);
}

// V3: + real global_load_lds stream (R6 rotation, vmcnt(4)/tile), frags fixed.
template<int VM>
__device__ __forceinline__ void v3tile(
    int t, bf16x8 (&f0)[4], bf16x8 (&f1)[4], bf16x8 (&g0)[2], bf16x8 (&g1)[2],
    ushort_t (&dB1)[8192], ushort_t (&dA1)[8192],
    ushort_t (&dB0)[8192], ushort_t (&dA0)[8192],
    int wid, const ushort_t* pa0, const ushort_t* pa1,
    const ushort_t* pb0, const ushort_t* pb1, f32x4 (&acc)[8][4]) {
  const size_t c1 = (size_t)((t + 1) & 63) * 64, c2 = (size_t)((t + 2) & 63) * 64;
  stg(pb0 + (size_t)128 * K_DIM + c1, pb1 + (size_t)128 * K_DIM + c1, dB1, wid);
  vmfma(acc, f0, f1, g0, g1, 0, 0); BARR();
  stg(pa0 + (size_t)128 * K_DIM + c1, pa1 + (size_t)128 * K_DIM + c1, dA1, wid);
  vmfma(acc, f0, f1, g0, g1, 0, 2); BARR();
  stg(pb0 + c2, pb1 + c2, dB0, wid);
  vmfma(acc, f0, f1, g0, g1, 4, 2); BARR();
  stg(pa0 + c2, pa1 + c2, dA0, wid);
  vmfma(acc, f0, f1, g0, g1, 4, 0);
  asm volatile("s_waitcnt vmcnt(%0)" :: "i"(VM));
  __builtin_amdgcn_sched_barrier(0);
  BARR();
}

__global__ __launch_bounds__(512, 2) void gv3_dma(const ushort_t* __restrict__ A,
                                                  const ushort_t* __restrict__ B,
                                                  float* __restrict__ D) {
  __shared__ ushort_t sA0p0[8192], sA0p1[8192], sA1p0[8192], sA1p1[8192];
  __shared__ ushort_t sB0p0[8192], sB0p1[8192], sB1p0[8192], sB1p1[8192];
  const int tid = threadIdx.x, wid = tid >> 6, lane = tid & 63;
  const int r = lane & 15, h = lane >> 4, wm = wid >> 2, wn = wid & 3;
  const int bn = blockIdx.x, bm = blockIdx.y;
  const int x7 = lane & 7;
  const int swz0 = ((h) ^ x7) << 3, swz1 = ((4 | h) ^ x7) << 3;
  const int srow0 = tid >> 3;
  const int cst = ((tid & 7) ^ (srow0 & 7)) << 3;
  const ushort_t* pa0 = A + (size_t)(bm * 256 + srow0) * K_DIM + cst;
  const ushort_t* pa1 = A + (size_t)(bm * 256 + 64 + srow0) * K_DIM + cst;
  const ushort_t* pb0 = B + (size_t)(bn * 256 + srow0) * K_DIM + cst;
  const ushort_t* pb1 = B + (size_t)(bn * 256 + 64 + srow0) * K_DIM + cst;

  stg(pb0, pb1, sB0p0, wid);
  stg(pa0, pa1, sA0p0, wid);
  stg(pb0 + (size_t)128 * K_DIM, pb1 + (size_t)128 * K_DIM, sB1p0, wid);
  stg(pa0 + (size_t)128 * K_DIM, pa1 + (size_t)128 * K_DIM, sA1p0, wid);
  stg(pb0 + 64, pb1 + 64, sB0p1, wid);
  stg(pa0 + 64, pa1 + 64, sA0p1, wid);
  asm volatile("s_waitcnt vmcnt(4)");
  __builtin_amdgcn_sched_barrier(0);
  BARR();

  bf16x8 f0[4], f1[4], g0[2], g1[2];
  #pragma unroll
  for (int i = 0; i < 4; ++i) {
    f0[i] = lds_ld(&sA0p0[(i * 16 + r) * 64 + swz0]);
    f1[i] = lds_ld(&sA0p0[(i * 16 + r) * 64 + swz1]);
  }
  #pragma unroll
  for (int n = 0; n < 2; ++n) {
    g0[n] = lds_ld(&sB0p0[((wn & 1) * 64 + n * 16 + r) * 64 + swz0]);
    g1[n] = lds_ld(&sB0p0[((wn & 1) * 64 + n * 16 + r) * 64 + swz1]);
  }
  f32x4 acc[8][4];
  #pragma unroll
  for (int m = 0; m < 8; ++m)
    #pragma unroll
    for (int n = 0; n < 4; ++n) acc[m][n] = (f32x4){0.f, 0.f, 0.f, 0.f};

  for (int t = 0; t < 64; t += 2) {
    v3tile<4>(t,     f0, f1, g0, g1, sB1p1, sA1p1, sB0p0, sA0p0, wid, pa0, pa1, pb0, pb1, acc);
    v3tile<4>(t + 1, f0, f1, g0, g1, sB1p0, sA1p0, sB0p1, sA0p1, wid, pa0, pa1, pb0, pb1, acc);
  }
  asm volatile("s_waitcnt vmcnt(0)");
  vepi(acc, D, bm, bn, wm, wn, r, h);
}

// Emergency fallback if ws is too small: fused fp32, slow but correct.
__global__ __launch_bounds__(256) void fused_naive(const float* __restrict__ x,
                                                   const float* __restrict__ w,
                                                   const float* __restrict__ bias,
                                                   float* __restrict__ out) {
  __shared__ float xq[K_DIM];
  const int row = blockIdx.x;
  const float* xr = x + (size_t)row * K_DIM;
  const int t = threadIdx.x;
  const int g = t >> 3, s = t & 7;
  float vals[16];
  float amax = 0.f;
  #pragma unroll
  for (int i = 0; i < 16; ++i) {
    vals[i] = xr[g * 128 + s * 16 + i];
    amax = fmaxf(amax, fabsf(vals[i]));
  }
  #pragma unroll
  for (int m = 1; m < 8; m <<= 1) amax = fmaxf(amax, __shfl_xor(amax, m, 64));
  float scale = amax / 6.0f;
  if (scale == 0.f) scale = 1.f;
  const float rs = 1.0f / scale;
  #pragma unroll
  for (int i = 0; i < 16; ++i) {
    float xs = vals[i] * rs;
    xq[g * 128 + s * 16 + i] = copysignf(snap(fabsf(xs)), xs) * scale;
  }
  __syncthreads();
  #pragma unroll
  for (int i = 0; i < 4; ++i) {
    const int o = i * 256 + t;
    const float* wrow = w + (size_t)o * K_DIM;
    float acc = 0.f;
    for (int k = 0; k < K_DIM; k += 4) {
      float4 wv = *reinterpret_cast<const float4*>(wrow + k);
      acc += xq[k] * wv.x + xq[k + 1] * wv.y + xq[k + 2] * wv.z + xq[k + 3] * wv.w;
    }
    out[(size_t)row * N_DIM + o] = acc + bias[o];
  }
}

extern "C" void kernel_launch(void* const* d_in, const int* in_sizes, int n_in,
                              void* d_out, int out_size, void* d_ws, size_t ws_size,
                              hipStream_t stream) {
  const float* x    = (const float*)d_in[0];
  const float* wgt  = (const float*)d_in[1];
  const float* bias = (const float*)d_in[2];
  float* out = (float*)d_out;

  const size_t deq_bytes = (size_t)M_DIM * K_DIM * 2;
  const size_t wb_bytes  = (size_t)N_DIM * K_DIM * 2;
  if (ws_size >= deq_bytes + wb_bytes) {
    ushort_t* deq = (ushort_t*)d_ws;
    ushort_t* wb  = (ushort_t*)((char*)d_ws + deq_bytes);
    quant_kernel<<<(M_DIM * (K_DIM / 128)) / 16, 256, 0, stream>>>(x, deq);
    wconv_kernel<<<1024, 256, 0, stream>>>(wgt, wb);
    gemm256<<<dim3(N_DIM / 256, M_DIM / 256), 512, 0, stream>>>(deq, wb, bias, out);
    // ---- diagnostic ablations: run AFTER d_out is produced; write garbage
    // into the now-dead deq region (scratch, never validated).
    float* dummy = (float*)deq;   // 64 MB C-shaped garbage fits in 128 MB region
    dim3 g(N_DIM / 256, M_DIM / 256);
    gv1_mfma<<<g, 512, 0, stream>>>(deq, wb, dummy);
    gv2_reads<<<g, 512, 0, stream>>>(deq, wb, dummy);
    gv3_dma<<<g, 512, 0, stream>>>(deq, wb, dummy);
  } else {
    fused_naive<<<M_DIM, 256, 0, stream>>>(x, wgt, bias, out);
  }
}

// Round 9
// 190.246 us; speedup vs baseline: 2.6113x; 2.6113x over previous
//
#include <hip/hip_runtime.h>
#include <hip/hip_bf16.h>

using bf16x8 = __attribute__((ext_vector_type(8))) __bf16;
using f32x4  = __attribute__((ext_vector_type(4))) float;
typedef unsigned short ushort_t;

#define M_DIM 16384
#define K_DIM 4096
#define N_DIM 1024

#define BARR() __builtin_amdgcn_s_barrier()

__device__ __forceinline__ unsigned short f2bf(float f) {
  __hip_bfloat16 h = __float2bfloat16(f);  // RNE
  return *reinterpret_cast<unsigned short*>(&h);
}

__device__ __forceinline__ float snap(float a) {
  float q = 0.0f;
  q += (a > 0.25f) ? 0.5f : 0.0f;
  q += (a > 0.75f) ? 0.5f : 0.0f;
  q += (a > 1.25f) ? 0.5f : 0.0f;
  q += (a > 1.75f) ? 0.5f : 0.0f;
  q += (a > 2.5f)  ? 1.0f : 0.0f;
  q += (a > 3.5f)  ? 1.0f : 0.0f;
  q += (a > 5.0f)  ? 2.0f : 0.0f;
  return q;
}

__device__ __forceinline__ unsigned short qdq(float xv, float rs, float scale) {
  float xs = xv * rs;
  float q  = copysignf(snap(fabsf(xs)), xs);
  return f2bf(q * scale);
}

__global__ __launch_bounds__(256) void quant_kernel(const float* __restrict__ x,
                                                    unsigned short* __restrict__ dq) {
  const int wid = (blockIdx.x << 2) + (threadIdx.x >> 6);
  const int l   = threadIdx.x & 63;
  const int sub = l >> 4, t = l & 15;
  const size_t base = ((size_t)wid * 4 + sub) * 128;
  const float4* px = reinterpret_cast<const float4*>(x + base);
  float4 v0 = px[t];
  float4 v1 = px[16 + t];
  float amax = fmaxf(fmaxf(fmaxf(fabsf(v0.x), fabsf(v0.y)), fmaxf(fabsf(v0.z), fabsf(v0.w))),
                     fmaxf(fmaxf(fabsf(v1.x), fabsf(v1.y)), fmaxf(fabsf(v1.z), fabsf(v1.w))));
  #pragma unroll
  for (int m = 1; m < 16; m <<= 1) amax = fmaxf(amax, __shfl_xor(amax, m, 64));
  float scale = amax / 6.0f;
  if (scale == 0.0f) scale = 1.0f;
  const float rs = 1.0f / scale;
  ushort4 o0, o1;
  o0.x = qdq(v0.x, rs, scale); o0.y = qdq(v0.y, rs, scale);
  o0.z = qdq(v0.z, rs, scale); o0.w = qdq(v0.w, rs, scale);
  o1.x = qdq(v1.x, rs, scale); o1.y = qdq(v1.y, rs, scale);
  o1.z = qdq(v1.z, rs, scale); o1.w = qdq(v1.w, rs, scale);
  reinterpret_cast<ushort4*>(dq + base)[t]      = o0;
  reinterpret_cast<ushort4*>(dq + base)[16 + t] = o1;
}

__global__ __launch_bounds__(256) void wconv_kernel(const float* __restrict__ w,
                                                    unsigned short* __restrict__ o) {
  const int n4 = (N_DIM * K_DIM) / 4;
  for (int i = blockIdx.x * 256 + threadIdx.x; i < n4; i += gridDim.x * 256) {
    float4 v = reinterpret_cast<const float4*>(w)[i];
    ushort4 u;
    u.x = f2bf(v.x); u.y = f2bf(v.y); u.z = f2bf(v.z); u.w = f2bf(v.w);
    reinterpret_cast<ushort4*>(o)[i] = u;
  }
}

__device__ __forceinline__ bf16x8 lds_ld(const ushort_t* p) {
  return *reinterpret_cast<const bf16x8*>(p);
}

// Stage one 16KB half-tile into sL at compile-time offset OFF (linear dest;
// swizzle pre-applied on the global source, T21).
template<int OFF>
__device__ __forceinline__ void stg2(ushort_t (&sL)[65536], int wid,
                                     const ushort_t* g0, const ushort_t* g1) {
  __builtin_amdgcn_global_load_lds((const __attribute__((address_space(1))) void*)g0,
      (__attribute__((address_space(3))) void*)(&sL[OFF + wid * 512]), 16, 0, 0);
  __builtin_amdgcn_global_load_lds((const __attribute__((address_space(1))) void*)g1,
      (__attribute__((address_space(3))) void*)(&sL[OFF + 4096 + wid * 512]), 16, 0, 0);
}

// Single LDS array, parity P compile-time (2-tile unroll), wave-half via
// runtime-uniform offsets rab/rbb — ONE code path for all 8 waves (m201
// structure; replaces R5-R8's 4x krun<WM,WH> clone, suspected I-cache thrash).
// Layout (ushorts): parity P at P*32768; within: A0=0, A1=8192, B0=16384, B1=24576.
// Phase = {ds_reads; stage 1 half-tile; BAR; lgkmcnt(0); setprio+16 MFMA; BAR};
// counted vmcnt(4) once per tile at ph4 (ledger verified: completes exactly
// tile t+1's four half-tiles; 2 stay in flight).
template<int P, bool S12, bool S34, int VM>
__device__ __forceinline__ void tile_iter(
    int t, ushort_t (&sL)[65536], int wid, int rab, int rbb,
    const int (&roA)[8], const int (&roB)[4], int swz0, int swz1,
    const ushort_t* pa0, const ushort_t* pa1,
    const ushort_t* pb0, const ushort_t* pb1,
    f32x4 (&acc)[8][4]) {
  constexpr int RP  = P * 32768;
  constexpr int DB1 = (1 - P) * 32768 + 24576;   // B-half1(t+1), parity 1-P
  constexpr int DA1 = (1 - P) * 32768 + 8192;    // A-half1(t+1)
  constexpr int DB0 = P * 32768 + 16384;         // B-half0(t+2), parity P (free after ph2)
  constexpr int DA0 = P * 32768;                 // A-half0(t+2)  (free after ph3)
  bf16x8 aL0[4], aL1[4], aH0[4], aH1[4], b0[4], b1[4];

  // ---- ph1: read aL(8) + b01(4); stage B1(t+1); BAR; lgkm0; MFMA aL x b01; BAR
  #pragma unroll
  for (int i = 0; i < 4; ++i) {
    aL0[i] = lds_ld(&sL[RP + rab + roA[i] + swz0]);
    aL1[i] = lds_ld(&sL[RP + rab + roA[i] + swz1]);
  }
  #pragma unroll
  for (int n = 0; n < 2; ++n) {
    b0[n] = lds_ld(&sL[RP + rbb + roB[n] + swz0]);
    b1[n] = lds_ld(&sL[RP + rbb + roB[n] + swz1]);
  }
  if constexpr (S12)
    stg2<DB1>(sL, wid, pb0 + (size_t)128 * K_DIM + (size_t)(t + 1) * 64,
                       pb1 + (size_t)128 * K_DIM + (size_t)(t + 1) * 64);
  BARR();
  asm volatile("s_waitcnt lgkmcnt(0)");
  __builtin_amdgcn_s_setprio(1);
  #pragma unroll
  for (int i = 0; i < 4; ++i)
    #pragma unroll
    for (int n = 0; n < 2; ++n) {
      acc[i][n] = __builtin_amdgcn_mfma_f32_16x16x32_bf16(aL0[i], b0[n], acc[i][n], 0, 0, 0);
      acc[i][n] = __builtin_amdgcn_mfma_f32_16x16x32_bf16(aL1[i], b1[n], acc[i][n], 0, 0, 0);
    }
  __builtin_amdgcn_s_setprio(0);
  BARR();

  // ---- ph2: read b23(4); stage A1(t+1); BAR; lgkm0; MFMA aL x b23; BAR
  #pragma unroll
  for (int n = 2; n < 4; ++n) {
    b0[n] = lds_ld(&sL[RP + rbb + roB[n] + swz0]);
    b1[n] = lds_ld(&sL[RP + rbb + roB[n] + swz1]);
  }
  if constexpr (S12)
    stg2<DA1>(sL, wid, pa0 + (size_t)128 * K_DIM + (size_t)(t + 1) * 64,
                       pa1 + (size_t)128 * K_DIM + (size_t)(t + 1) * 64);
  BARR();
  asm volatile("s_waitcnt lgkmcnt(0)");
  __builtin_amdgcn_s_setprio(1);
  #pragma unroll
  for (int i = 0; i < 4; ++i)
    #pragma unroll
    for (int n = 2; n < 4; ++n) {
      acc[i][n] = __builtin_amdgcn_mfma_f32_16x16x32_bf16(aL0[i], b0[n], acc[i][n], 0, 0, 0);
      acc[i][n] = __builtin_amdgcn_mfma_f32_16x16x32_bf16(aL1[i], b1[n], acc[i][n], 0, 0, 0);
    }
  __builtin_amdgcn_s_setprio(0);
  BARR();

  // ---- ph3: read aH(8); stage B0(t+2); BAR; lgkm0; MFMA aH x b23; BAR
  #pragma unroll
  for (int i = 0; i < 4; ++i) {
    aH0[i] = lds_ld(&sL[RP + rab + roA[4 + i] + swz0]);
    aH1[i] = lds_ld(&sL[RP + rab + roA[4 + i] + swz1]);
  }
  if constexpr (S34)
    stg2<DB0>(sL, wid, pb0 + (size_t)(t + 2) * 64, pb1 + (size_t)(t + 2) * 64);
  BARR();
  asm volatile("s_waitcnt lgkmcnt(0)");
  __builtin_amdgcn_s_setprio(1);
  #pragma unroll
  for (int i = 0; i < 4; ++i)
    #pragma unroll
    for (int n = 2; n < 4; ++n) {
      acc[4 + i][n] = __builtin_amdgcn_mfma_f32_16x16x32_bf16(aH0[i], b0[n], acc[4 + i][n], 0, 0, 0);
      acc[4 + i][n] = __builtin_amdgcn_mfma_f32_16x16x32_bf16(aH1[i], b1[n], acc[4 + i][n], 0, 0, 0);
    }
  __builtin_amdgcn_s_setprio(0);
  BARR();

  // ---- ph4: stage A0(t+2); BAR; MFMA aH x b01; vmcnt; BAR
  if constexpr (S34)
    stg2<DA0>(sL, wid, pa0 + (size_t)(t + 2) * 64, pa1 + (size_t)(t + 2) * 64);
  BARR();
  __builtin_amdgcn_s_setprio(1);
  #pragma unroll
  for (int i = 0; i < 4; ++i)
    #pragma unroll
    for (int n = 0; n < 2; ++n) {
      acc[4 + i][n] = __builtin_amdgcn_mfma_f32_16x16x32_bf16(aH0[i], b0[n], acc[4 + i][n], 0, 0, 0);
      acc[4 + i][n] = __builtin_amdgcn_mfma_f32_16x16x32_bf16(aH1[i], b1[n], acc[4 + i][n], 0, 0, 0);
    }
  __builtin_amdgcn_s_setprio(0);
  if constexpr (VM == 4) {
    asm volatile("s_waitcnt vmcnt(4)");
    __builtin_amdgcn_sched_barrier(0);   // rule #18: next tile's ds_reads stay below
  } else if constexpr (VM == 0) {
    asm volatile("s_waitcnt vmcnt(0)");
    __builtin_amdgcn_sched_barrier(0);
  }
  BARR();
}

// 256x256 tile, BK=64, 8 waves (2M x 4N), single-path 8-phase schedule,
// XOR swizzle, counted vmcnt. A = deq [M,K], B = W [N,K] (row-major bf16).
__global__ __launch_bounds__(512, 2) void gemm256(const ushort_t* __restrict__ A,
                                                  const ushort_t* __restrict__ B,
                                                  const float* __restrict__ bias,
                                                  float* __restrict__ C) {
  __shared__ ushort_t sL[65536];   // 128 KiB: [parity][A0|A1|B0|B1] x 8192
  const int tid  = threadIdx.x;
  const int wid  = tid >> 6, lane = tid & 63;
  const int r    = lane & 15, h = lane >> 4;
  const int wm   = wid >> 2, wn = wid & 3;
  const int bn   = blockIdx.x, bm = blockIdx.y;

  // ds_read swizzle: col16-slice = (kk*4+h) ^ (row&7); row&7 == lane&7.
  const int x7   = lane & 7;
  const int swz0 = ((h) ^ x7) << 3;
  const int swz1 = ((4 | h) ^ x7) << 3;
  int roA[8], roB[4];
  #pragma unroll
  for (int m = 0; m < 8; ++m) roA[m] = (m * 16 + r) * 64;
  #pragma unroll
  for (int n = 0; n < 4; ++n) roB[n] = ((wn & 1) * 64 + n * 16 + r) * 64;
  const int rab = wm * 8192;                  // wave's A half slot offset
  const int rbb = 16384 + (wn >> 1) * 8192;   // wave's B half slot offset

  // staging source: LDS row = tid>>3, 16B-slice q = tid&7,
  // global slice = q ^ (row&7) (inverse of the read-side XOR).
  const int srow0 = tid >> 3;
  const int cst   = ((tid & 7) ^ (srow0 & 7)) << 3;
  const ushort_t* pa0 = A + (size_t)(bm * 256 + srow0) * K_DIM + cst;
  const ushort_t* pa1 = A + (size_t)(bm * 256 + 64 + srow0) * K_DIM + cst;
  const ushort_t* pb0 = B + (size_t)(bn * 256 + srow0) * K_DIM + cst;
  const ushort_t* pb1 = B + (size_t)(bn * 256 + 64 + srow0) * K_DIM + cst;

  f32x4 acc[8][4];
  #pragma unroll
  for (int m = 0; m < 8; ++m)
    #pragma unroll
    for (int n = 0; n < 4; ++n) acc[m][n] = (f32x4){0.f, 0.f, 0.f, 0.f};

  // Prologue: tile0 {B0,A0,B1,A1} + tile1 {B0,A0}; vmcnt(4) leaves tile1's
  // two half-tiles in flight.
  stg2<16384>(sL, wid, pb0, pb1);                                              // B0(0)
  stg2<0>    (sL, wid, pa0, pa1);                                              // A0(0)
  stg2<24576>(sL, wid, pb0 + (size_t)128 * K_DIM, pb1 + (size_t)128 * K_DIM);  // B1(0)
  stg2<8192> (sL, wid, pa0 + (size_t)128 * K_DIM, pa1 + (size_t)128 * K_DIM);  // A1(0)
  stg2<49152>(sL, wid, pb0 + 64, pb1 + 64);                                    // B0(1)
  stg2<32768>(sL, wid, pa0 + 64, pa1 + 64);                                    // A0(1)
  asm volatile("s_waitcnt vmcnt(4)");
  __builtin_amdgcn_sched_barrier(0);
  BARR();

  for (int t = 0; t < 62; t += 2) {   // parity compile-time via 2-tile unroll
    tile_iter<0, true, true, 4>(t,     sL, wid, rab, rbb, roA, roB, swz0, swz1,
                                pa0, pa1, pb0, pb1, acc);
    tile_iter<1, true, true, 4>(t + 1, sL, wid, rab, rbb, roA, roB, swz0, swz1,
                                pa0, pa1, pb0, pb1, acc);
  }
  tile_iter<0, true, false, 0>(62, sL, wid, rab, rbb, roA, roB, swz0, swz1,
                               pa0, pa1, pb0, pb1, acc);
  tile_iter<1, false, false, -1>(63, sL, wid, rab, rbb, roA, roB, swz0, swz1,
                                 pa0, pa1, pb0, pb1, acc);

  // Epilogue: C/D layout col=lane&15, row=(lane>>4)*4+reg  [m89/m91]
  const int orow = bm * 256 + wm * 128;
  const int ocol = bn * 256 + wn * 64;
  #pragma unroll
  for (int n = 0; n < 4; ++n) {
    const int col = ocol + n * 16 + r;
    const float bv = bias[col];
    #pragma unroll
    for (int m = 0; m < 8; ++m) {
      const int rb = orow + m * 16 + h * 4;
      #pragma unroll
      for (int j = 0; j < 4; ++j)
        C[(size_t)(rb + j) * N_DIM + col] = acc[m][n][j] + bv;
    }
  }
}

// Emergency fallback if ws is too small: fused fp32, slow but correct.
__global__ __launch_bounds__(256) void fused_naive(const float* __restrict__ x,
                                                   const float* __restrict__ w,
                                                   const float* __restrict__ bias,
                                                   float* __restrict__ out) {
  __shared__ float xq[K_DIM];
  const int row = blockIdx.x;
  const float* xr = x + (size_t)row * K_DIM;
  const int t = threadIdx.x;
  const int g = t >> 3, s = t & 7;
  float vals[16];
  float amax = 0.f;
  #pragma unroll
  for (int i = 0; i < 16; ++i) {
    vals[i] = xr[g * 128 + s * 16 + i];
    amax = fmaxf(amax, fabsf(vals[i]));
  }
  #pragma unroll
  for (int m = 1; m < 8; m <<= 1) amax = fmaxf(amax, __shfl_xor(amax, m, 64));
  float scale = amax / 6.0f;
  if (scale == 0.f) scale = 1.f;
  const float rs = 1.0f / scale;
  #pragma unroll
  for (int i = 0; i < 16; ++i) {
    float xs = vals[i] * rs;
    xq[g * 128 + s * 16 + i] = copysignf(snap(fabsf(xs)), xs) * scale;
  }
  __syncthreads();
  #pragma unroll
  for (int i = 0; i < 4; ++i) {
    const int o = i * 256 + t;
    const float* wrow = w + (size_t)o * K_DIM;
    float acc = 0.f;
    for (int k = 0; k < K_DIM; k += 4) {
      float4 wv = *reinterpret_cast<const float4*>(wrow + k);
      acc += xq[k] * wv.x + xq[k + 1] * wv.y + xq[k + 2] * wv.z + xq[k + 3] * wv.w;
    }
    out[(size_t)row * N_DIM + o] = acc + bias[o];
  }
}

extern "C" void kernel_launch(void* const* d_in, const int* in_sizes, int n_in,
                              void* d_out, int out_size, void* d_ws, size_t ws_size,
                              hipStream_t stream) {
  const float* x    = (const float*)d_in[0];
  const float* wgt  = (const float*)d_in[1];
  const float* bias = (const float*)d_in[2];
  float* out = (float*)d_out;

  const size_t deq_bytes = (size_t)M_DIM * K_DIM * 2;
  const size_t wb_bytes  = (size_t)N_DIM * K_DIM * 2;
  if (ws_size >= deq_bytes + wb_bytes) {
    ushort_t* deq = (ushort_t*)d_ws;
    ushort_t* wb  = (ushort_t*)((char*)d_ws + deq_bytes);
    quant_kernel<<<(M_DIM * (K_DIM / 128)) / 16, 256, 0, stream>>>(x, deq);
    wconv_kernel<<<1024, 256, 0, stream>>>(wgt, wb);
    gemm256<<<dim3(N_DIM / 256, M_DIM / 256), 512, 0, stream>>>(deq, wb, bias, out);
  } else {
    fused_naive<<<M_DIM, 256, 0, stream>>>(x, wgt, bias, out);
  }
}